// Round 2
// baseline (367.220 us; speedup 1.0000x reference)
//
#include <hip/hip_runtime.h>
#include <stdint.h>

// set attention: N=32, L=256, D=20, heads=2, head_dim=20. ALL I/O fp32
// (reference dtypes; R1's NaN proved inputs are fp32 — fp32 misread as bf16
// yields NaN-exponent patterns, bf16 misread never can).
// Output batch P (flat [P/32][P%32]): Q from x-batch P, K/V from y-batch
// ((P&31)<<5)|(P>>5)  [verified against reference transpose chain].

#define NSET 32
#define SEQL 256
#define DM   20   // model dim
#define NH   2
#define DH   20   // head dim
#define HD   40   // NH*DH

__device__ __forceinline__ float bflo(uint32_t u) { return __uint_as_float(u << 16); }
__device__ __forceinline__ float bfhi(uint32_t u) { return __uint_as_float(u & 0xffff0000u); }
__device__ __forceinline__ uint32_t bfbits(float f) {
    uint32_t u = __float_as_uint(f);
    return ((u + 0x7fffu + ((u >> 16) & 1u)) >> 16) & 0xffffu;  // RNE
}
__device__ __forceinline__ uint2 packbf4(float a, float b, float c, float d) {
    return make_uint2(bfbits(a) | (bfbits(b) << 16), bfbits(c) | (bfbits(d) << 16));
}

__global__ __launch_bounds__(256, 2) void set_attn_kernel(
    const float* __restrict__ x,
    const float* __restrict__ y,
    const float* __restrict__ wq,
    const float* __restrict__ wk,
    const float* __restrict__ wv,
    const float* __restrict__ wh,
    float* __restrict__ out)
{
    // LDS: weights fp32 12.8 KB + K fp32 40 KB + V bf16 20 KB = 72.5 KB -> 2 blocks/CU
    __shared__ float sWQ[DM * HD];
    __shared__ float sWK[DM * HD];
    __shared__ float sWV[DM * HD];
    __shared__ float sWH[HD * DH];
    __shared__ float sKf[SEQL * HD];   // row s: [s*40 + h*20 + d], fp32
    __shared__ uint2 sV [SEQL * 10];   // row s: [s*10 + h*5 + r], 4 bf16 per uint2

    const int t = threadIdx.x;   // query row / kv row owned by this thread
    const int b = blockIdx.x;    // output batch P
    const int i = b >> 5;
    const int j = b & 31;

    // ---- stage weights (fp32) ----
    for (int idx = t; idx < DM * HD; idx += 256) {
        sWQ[idx] = wq[idx];
        sWK[idx] = wk[idx];
        sWV[idx] = wv[idx];
        sWH[idx] = wh[idx];   // HD*DH == DM*HD == 800
    }

    // ---- load this thread's x row (batch b) and y row (batch j*32+i) ----
    // rows are 20 floats = 80 B, 16-byte aligned -> float4 x5
    const float4* xp = (const float4*)(x + ((size_t)b * SEQL + t) * DM);
    const float4* yp = (const float4*)(y + ((size_t)(j * NSET + i) * SEQL + t) * DM);
    float xr[DM], yr[DM];
#pragma unroll
    for (int w = 0; w < 5; ++w) {
        float4 ux = xp[w], uy = yp[w];
        xr[4*w+0] = ux.x; xr[4*w+1] = ux.y; xr[4*w+2] = ux.z; xr[4*w+3] = ux.w;
        yr[4*w+0] = uy.x; yr[4*w+1] = uy.y; yr[4*w+2] = uy.z; yr[4*w+3] = uy.w;
    }
    __syncthreads();

    // ---- K projection: k[t][m] = sum_d y[t][d] * WK[d][m]; fp32 to LDS ----
    {
        float acc[HD];
#pragma unroll
        for (int m = 0; m < HD; ++m) acc[m] = 0.f;
#pragma unroll
        for (int d = 0; d < DM; ++d) {
            float yd = yr[d];
#pragma unroll
            for (int m = 0; m < HD; ++m) acc[m] = fmaf(yd, sWK[d * HD + m], acc[m]);
        }
        float4* kw = (float4*)&sKf[t * HD];
#pragma unroll
        for (int w = 0; w < 10; ++w)
            kw[w] = make_float4(acc[4*w], acc[4*w+1], acc[4*w+2], acc[4*w+3]);
    }
    // ---- V projection: bf16-packed to LDS ----
    {
        float acc[HD];
#pragma unroll
        for (int m = 0; m < HD; ++m) acc[m] = 0.f;
#pragma unroll
        for (int d = 0; d < DM; ++d) {
            float yd = yr[d];
#pragma unroll
            for (int m = 0; m < HD; ++m) acc[m] = fmaf(yd, sWV[d * HD + m], acc[m]);
        }
#pragma unroll
        for (int w = 0; w < 10; ++w)
            sV[t * 10 + w] = packbf4(acc[4*w], acc[4*w+1], acc[4*w+2], acc[4*w+3]);
    }
    // ---- Q projection (registers, fp32) ----
    float q[HD];
    {
#pragma unroll
        for (int m = 0; m < HD; ++m) q[m] = 0.f;
#pragma unroll
        for (int d = 0; d < DM; ++d) {
            float xd = xr[d];
#pragma unroll
            for (int m = 0; m < HD; ++m) q[m] = fmaf(xd, sWQ[d * HD + m], q[m]);
        }
    }
    __syncthreads();

    // ---- attention per head: max-free masked softmax ----
    // ref: mask=(logit!=0); z=exp(logit-max); z/(sum+1e-10). |logit|<~8 so the
    // max-subtraction cancels exactly in the ratio; exp cannot overflow.
    const float scale = 0.22360679774997896f;  // 1/sqrt(20)
    float oall[HD];
#pragma unroll
    for (int h = 0; h < NH; ++h) {
        float l = 0.f;
        float o[DH];
#pragma unroll
        for (int d = 0; d < DH; ++d) o[d] = 0.f;

        for (int s = 0; s < SEQL; ++s) {
            const float4* kr = (const float4*)&sKf[s * HD + h * DH];  // uniform -> broadcast
            float a0 = 0.f, a1 = 0.f, a2 = 0.f, a3 = 0.f;
#pragma unroll
            for (int r = 0; r < 5; ++r) {
                float4 kv = kr[r];
                a0 = fmaf(q[h * DH + 4*r + 0], kv.x, a0);
                a1 = fmaf(q[h * DH + 4*r + 1], kv.y, a1);
                a2 = fmaf(q[h * DH + 4*r + 2], kv.z, a2);
                a3 = fmaf(q[h * DH + 4*r + 3], kv.w, a3);
            }
            float L = ((a0 + a1) + (a2 + a3)) * scale;
            float p = (L != 0.f) ? __expf(L) : 0.f;   // custom zero-logit mask
            l += p;
            const uint2* vr = &sV[s * 10 + h * 5];    // uniform -> broadcast
#pragma unroll
            for (int r = 0; r < 5; ++r) {
                uint2 u = vr[r];
                o[4*r + 0] = fmaf(p, bflo(u.x), o[4*r + 0]);
                o[4*r + 1] = fmaf(p, bfhi(u.x), o[4*r + 1]);
                o[4*r + 2] = fmaf(p, bflo(u.y), o[4*r + 2]);
                o[4*r + 3] = fmaf(p, bfhi(u.y), o[4*r + 3]);
            }
        }
        float inv = 1.f / (l + 1e-10f);
#pragma unroll
        for (int d = 0; d < DH; ++d) oall[h * DH + d] = o[d] * inv;
    }

    // ---- output projection: res[d] = sum_m oall[m] * WH[m][d] ----
    float res[DH];
#pragma unroll
    for (int d = 0; d < DH; ++d) res[d] = 0.f;
#pragma unroll
    for (int m = 0; m < HD; ++m) {
        float om = oall[m];
#pragma unroll
        for (int d = 0; d < DH; ++d) res[d] = fmaf(om, sWH[m * DH + d], res[d]);
    }

    float4* op = (float4*)(out + ((size_t)b * SEQL + t) * DM);
#pragma unroll
    for (int w = 0; w < 5; ++w)
        op[w] = make_float4(res[4*w], res[4*w+1], res[4*w+2], res[4*w+3]);
}

extern "C" void kernel_launch(void* const* d_in, const int* in_sizes, int n_in,
                              void* d_out, int out_size, void* d_ws, size_t ws_size,
                              hipStream_t stream) {
    const float* x  = (const float*)d_in[0];
    const float* y  = (const float*)d_in[1];
    const float* wq = (const float*)d_in[2];
    const float* wk = (const float*)d_in[3];
    const float* wv = (const float*)d_in[4];
    const float* wh = (const float*)d_in[5];
    float* out = (float*)d_out;

    dim3 grid(NSET * NSET);   // 1024 batches
    dim3 block(SEQL);         // thread t = query row t
    set_attn_kernel<<<grid, block, 0, stream>>>(x, y, wq, wk, wv, wh, out);
}

// Round 3
// 304.621 us; speedup vs baseline: 1.2055x; 1.2055x over previous
//
#include <hip/hip_runtime.h>
#include <hip/hip_bf16.h>
#include <stdint.h>

// set attention, MFMA rewrite. N=32, L=256, D=20, H=2, Dh=20. fp32 I/O.
// Out batch b: Q from x[b], K/V from y[(b&31)*32 + (b>>5)]  (verified R2).
// All GEMMs via mfma_f32_16x16x32_bf16:
//   S^T = K·Q^T  (C-layout gives 4 consecutive s per lane -> b64 P pack)
//   O   = P·V    (P m-major stride-40 LDS, V^T row-major stride-264)
//   projections and out-proj also MFMA (W B-frags gathered per head).

#define NSET 32
#define SEQL 256
#define DM   20
#define NH   2
#define DH   20

typedef __attribute__((ext_vector_type(8))) short short8;
typedef __attribute__((ext_vector_type(4))) float f32x4;

#define MFMA(a, b, c) __builtin_amdgcn_mfma_f32_16x16x32_bf16((a), (b), (c), 0, 0, 0)

__device__ __forceinline__ uint32_t bfbits_rne(float f) {
    uint32_t u = __float_as_uint(f);
    return ((u + 0x7fffu + ((u >> 16) & 1u)) >> 16) & 0xffffu;  // RNE
}

// A-frag from k-quad-major region [3][256][8] (quad3 = implicit zeros)
__device__ __forceinline__ short8 load_afrag(const short* base, int row, int qd) {
    short8 f = {0, 0, 0, 0, 0, 0, 0, 0};
    if (qd < 3) f = *(const short8*)(base + qd * 2048 + row * 8);
    return f;
}

// B-frag gather from a bf16 weight matrix: f[j] = W[(row0 + qd*8 + j)*ldn + col0 + nl]
__device__ __forceinline__ short8 build_wfrag(const short* Wb, int ldn, int col0,
                                              int row0, int nl, int qd) {
    short8 f = {0, 0, 0, 0, 0, 0, 0, 0};
#pragma unroll
    for (int j = 0; j < 8; ++j) {
        int k = qd * 8 + j;
        if (k < 20 && nl < 20) f[j] = Wb[(row0 + k) * ldn + col0 + nl];
    }
    return f;
}

__global__ __launch_bounds__(256, 2) void set_attn_mfma(
    const float* __restrict__ x, const float* __restrict__ y,
    const float* __restrict__ wq, const float* __restrict__ wk,
    const float* __restrict__ wv, const float* __restrict__ wh,
    float* __restrict__ out)
{
    // 71.75 KB total -> 2 blocks/CU
    __shared__ __align__(16) short sQ[3 * 256 * 8];    // Q (then O) k-quad-major, 12 KB
    __shared__ __align__(16) short sK[3 * 256 * 8];    // K k-quad-major, 12 KB
    __shared__ __align__(16) short sVt[32 * 264];      // V^T [d][s], stride 264, 16.5 KB
    __shared__ __align__(16) short sReg[12288];        // Xs/Ys staging, then P_buf, 24 KB
    __shared__ float sL[4 * 64];                       // per-wave row sums, 1 KB
    __shared__ __align__(16) short sWb[3200];          // bf16 WQ|WK|WV|WH, 6.4 KB

    const int tid  = threadIdx.x;
    const int lane = tid & 63;
    const int w    = tid >> 6;     // wave 0..3, owns rows w*64..w*64+63
    const int c    = lane & 15;    // col-in-tile
    const int qd   = lane >> 4;    // k-quad / row-quad
    const int b    = blockIdx.x;
    const int bi   = b >> 5, bj = b & 31;

    // ---- one-time: stage weights bf16; zero k-pads ----
    for (int i = tid; i < 800; i += 256) {
        sWb[i]        = (short)bfbits_rne(wq[i]);
        sWb[800 + i]  = (short)bfbits_rne(wk[i]);
        sWb[1600 + i] = (short)bfbits_rne(wv[i]);
        sWb[2400 + i] = (short)bfbits_rne(wh[i]);
    }
#pragma unroll
    for (int j = 4; j < 8; ++j) {              // k=20..23 pad in quad2
        sQ[2 * 2048 + tid * 8 + j] = 0;
        sK[2 * 2048 + tid * 8 + j] = 0;
    }
    for (int i = tid; i < 12 * 264; i += 256) sVt[20 * 264 + i] = 0;  // d=20..31 pad rows

    f32x4 outacc[4][2];
#pragma unroll
    for (int mt = 0; mt < 4; ++mt)
#pragma unroll
        for (int dt = 0; dt < 2; ++dt) outacc[mt][dt] = (f32x4){0.f, 0.f, 0.f, 0.f};

    const float scale = 0.22360679774997896f;  // 1/sqrt(20)
    short* sXs = sReg;
    short* sYs = sReg + 6144;
    short* pb  = sReg + w * 2560;              // per-wave P_buf [64][40] bf16

    for (int h = 0; h < NH; ++h) {
        __syncthreads();  // prev head's P_buf reads / Qs-Ks-Vt reads all done

        // ---- stage X,Y rows -> bf16 k-quad-major (thread t owns row t) ----
        {
            const float4* xp = (const float4*)(x + ((size_t)b * SEQL + tid) * DM);
            const float4* yp = (const float4*)(y + ((size_t)(bj * NSET + bi) * SEQL + tid) * DM);
            float xr[20], yr[20];
#pragma unroll
            for (int v4 = 0; v4 < 5; ++v4) {
                float4 a = xp[v4], bb = yp[v4];
                xr[4*v4] = a.x; xr[4*v4+1] = a.y; xr[4*v4+2] = a.z; xr[4*v4+3] = a.w;
                yr[4*v4] = bb.x; yr[4*v4+1] = bb.y; yr[4*v4+2] = bb.z; yr[4*v4+3] = bb.w;
            }
            uint32_t xb[10], yb[10];
#pragma unroll
            for (int p = 0; p < 10; ++p) {
                xb[p] = bfbits_rne(xr[2*p]) | (bfbits_rne(xr[2*p+1]) << 16);
                yb[p] = bfbits_rne(yr[2*p]) | (bfbits_rne(yr[2*p+1]) << 16);
            }
            uint32_t* X0 = (uint32_t*)&sXs[0 * 2048 + tid * 8];
            uint32_t* X1 = (uint32_t*)&sXs[1 * 2048 + tid * 8];
            uint32_t* X2 = (uint32_t*)&sXs[2 * 2048 + tid * 8];
            uint32_t* Y0 = (uint32_t*)&sYs[0 * 2048 + tid * 8];
            uint32_t* Y1 = (uint32_t*)&sYs[1 * 2048 + tid * 8];
            uint32_t* Y2 = (uint32_t*)&sYs[2 * 2048 + tid * 8];
#pragma unroll
            for (int p = 0; p < 4; ++p) { X0[p] = xb[p];     Y0[p] = yb[p]; }
#pragma unroll
            for (int p = 0; p < 4; ++p) { X1[p] = xb[4 + p]; Y1[p] = yb[4 + p]; }
            X2[0] = xb[8]; X2[1] = xb[9]; X2[2] = 0u; X2[3] = 0u;
            Y2[0] = yb[8]; Y2[1] = yb[9]; Y2[2] = 0u; Y2[3] = 0u;
        }
        __syncthreads();  // Xs/Ys visible

        // ---- projections via MFMA: Q,K -> k-quad-major; V -> V^T ----
        {
            short8 wqf[2], wkf[2], wvf[2];
#pragma unroll
            for (int dt = 0; dt < 2; ++dt) {
                int nl = dt * 16 + c;
                wqf[dt] = build_wfrag(sWb,        40, h * 20, 0, nl, qd);
                wkf[dt] = build_wfrag(sWb + 800,  40, h * 20, 0, nl, qd);
                wvf[dt] = build_wfrag(sWb + 1600, 40, h * 20, 0, nl, qd);
            }
#pragma unroll
            for (int mt = 0; mt < 4; ++mt) {
                int rbase = w * 64 + mt * 16;
                short8 xf = load_afrag(sXs, rbase + c, qd);
                short8 yf = load_afrag(sYs, rbase + c, qd);
#pragma unroll
                for (int dt = 0; dt < 2; ++dt) {
                    f32x4 z = {0.f, 0.f, 0.f, 0.f};
                    f32x4 qres = MFMA(xf, wqf[dt], z);
                    f32x4 kres = MFMA(yf, wkf[dt], z);
                    f32x4 vres = MFMA(yf, wvf[dt], z);
                    int n = dt * 16 + c;
                    if (n < 20) {
#pragma unroll
                        for (int reg = 0; reg < 4; ++reg) {
                            int row = rbase + qd * 4 + reg;
                            sQ[(n >> 3) * 2048 + row * 8 + (n & 7)] = (short)bfbits_rne(qres[reg]);
                            sK[(n >> 3) * 2048 + row * 8 + (n & 7)] = (short)bfbits_rne(kres[reg]);
                            sVt[n * 264 + row] = (short)bfbits_rne(vres[reg]);
                        }
                    }
                }
            }
        }
        __syncthreads();  // K, V^T complete (read cross-wave below)

        // ---- attention: S^T = K·Q^T, masked max-free softmax, O = P·V ----
        short8 qfrag[4];
#pragma unroll
        for (int mt = 0; mt < 4; ++mt) qfrag[mt] = load_afrag(sQ, w * 64 + mt * 16 + c, qd);

        f32x4 oacc[4][2];
#pragma unroll
        for (int mt = 0; mt < 4; ++mt)
#pragma unroll
            for (int dt = 0; dt < 2; ++dt) oacc[mt][dt] = (f32x4){0.f, 0.f, 0.f, 0.f};
        float lp0 = 0.f, lp1 = 0.f, lp2 = 0.f, lp3 = 0.f;

        for (int s0 = 0; s0 < 256; s0 += 32) {
            short8 kf0 = load_afrag(sK, s0 + c, qd);
            short8 kf1 = load_afrag(sK, s0 + 16 + c, qd);
#pragma unroll
            for (int mt = 0; mt < 4; ++mt) {
#pragma unroll
                for (int st = 0; st < 2; ++st) {
                    f32x4 z = {0.f, 0.f, 0.f, 0.f};
                    f32x4 sacc = MFMA((st == 0 ? kf0 : kf1), qfrag[mt], z);
                    uint32_t pu[4];
                    float lsum = 0.f;
#pragma unroll
                    for (int reg = 0; reg < 4; ++reg) {
                        float dotv = sacc[reg];
                        float e = __expf(dotv * scale);
                        float p = (dotv != 0.f) ? e : 0.f;   // ref zero-logit mask
                        uint32_t u = __float_as_uint(p) & 0xffff0000u;  // trunc bf16
                        lsum += __uint_as_float(u);          // l from SAME rounded P
                        pu[reg] = u;
                    }
                    if (mt == 0) lp0 += lsum;
                    else if (mt == 1) lp1 += lsum;
                    else if (mt == 2) lp2 += lsum;
                    else lp3 += lsum;
                    uint2 pw;
                    pw.x = (pu[0] >> 16) | pu[1];
                    pw.y = (pu[2] >> 16) | pu[3];
                    // P_buf[m][s]: m = mt*16+c, s = st*16 + qd*4 + {0..3}
                    *(uint2*)(pb + (mt * 16 + c) * 40 + (st * 16 + qd * 4)) = pw;
                }
            }
            // PV for this chunk (same-wave P_buf: compiler orders LDS rw)
            short8 vf0 = *(const short8*)(sVt + c * 264 + s0 + qd * 8);
            short8 vf1 = *(const short8*)(sVt + (16 + c) * 264 + s0 + qd * 8);
#pragma unroll
            for (int mt = 0; mt < 4; ++mt) {
                short8 pf = *(const short8*)(pb + (mt * 16 + c) * 40 + qd * 8);
                oacc[mt][0] = MFMA(pf, vf0, oacc[mt][0]);
                oacc[mt][1] = MFMA(pf, vf1, oacc[mt][1]);
            }
        }

        // ---- row sums: reduce over quads, broadcast via per-wave sL ----
        lp0 += __shfl_xor(lp0, 16, 64); lp0 += __shfl_xor(lp0, 32, 64);
        lp1 += __shfl_xor(lp1, 16, 64); lp1 += __shfl_xor(lp1, 32, 64);
        lp2 += __shfl_xor(lp2, 16, 64); lp2 += __shfl_xor(lp2, 32, 64);
        lp3 += __shfl_xor(lp3, 16, 64); lp3 += __shfl_xor(lp3, 32, 64);
        float sel = lp0;
        if (qd == 1) sel = lp1;
        if (qd == 2) sel = lp2;
        if (qd == 3) sel = lp3;
        sL[w * 64 + lane] = sel;           // index = m-in-wave = qd*16 + c

        float inv[4][4];
#pragma unroll
        for (int mt = 0; mt < 4; ++mt)
#pragma unroll
            for (int reg = 0; reg < 4; ++reg)
                inv[mt][reg] = 1.f / (sL[w * 64 + mt * 16 + qd * 4 + reg] + 1e-10f);

        // ---- normalize O, write bf16 into sQ region (own 64-row slice) ----
#pragma unroll
        for (int mt = 0; mt < 4; ++mt)
#pragma unroll
            for (int dt = 0; dt < 2; ++dt) {
                int d = dt * 16 + c;
                if (d < 20) {
#pragma unroll
                    for (int reg = 0; reg < 4; ++reg) {
                        int row = w * 64 + mt * 16 + qd * 4 + reg;
                        float ov = oacc[mt][dt][reg] * inv[mt][reg];
                        sQ[(d >> 3) * 2048 + row * 8 + (d & 7)] = (short)bfbits_rne(ov);
                    }
                }
            }

        // ---- out-projection: outacc += O_h · WH[h*20:(h+1)*20, :] ----
        short8 whf[2];
#pragma unroll
        for (int dt = 0; dt < 2; ++dt)
            whf[dt] = build_wfrag(sWb + 2400, 20, 0, h * 20, dt * 16 + c, qd);
#pragma unroll
        for (int mt = 0; mt < 4; ++mt) {
            short8 of = load_afrag(sQ, w * 64 + mt * 16 + c, qd);
            outacc[mt][0] = MFMA(of, whf[0], outacc[mt][0]);
            outacc[mt][1] = MFMA(of, whf[1], outacc[mt][1]);
        }
    }

    // ---- store ----
    float* ob = out + (size_t)b * (SEQL * DH);
#pragma unroll
    for (int mt = 0; mt < 4; ++mt)
#pragma unroll
        for (int dt = 0; dt < 2; ++dt) {
            int d = dt * 16 + c;
            if (d < 20) {
#pragma unroll
                for (int reg = 0; reg < 4; ++reg) {
                    int row = w * 64 + mt * 16 + qd * 4 + reg;
                    ob[row * 20 + d] = outacc[mt][dt][reg];
                }
            }
        }
}

extern "C" void kernel_launch(void* const* d_in, const int* in_sizes, int n_in,
                              void* d_out, int out_size, void* d_ws, size_t ws_size,
                              hipStream_t stream) {
    const float* x  = (const float*)d_in[0];
    const float* y  = (const float*)d_in[1];
    const float* wq = (const float*)d_in[2];
    const float* wk = (const float*)d_in[3];
    const float* wv = (const float*)d_in[4];
    const float* wh = (const float*)d_in[5];
    float* out = (float*)d_out;

    set_attn_mfma<<<dim3(NSET * NSET), dim3(SEQL), 0, stream>>>(x, y, wq, wk, wv, wh, out);
}

// Round 4
// 174.092 us; speedup vs baseline: 2.1093x; 1.7498x over previous
//
#include <hip/hip_runtime.h>
#include <stdint.h>

// set attention: N=32, L=256, D=20, H=2, Dh=20, fp32 I/O.
// Out batch b: Q from x[b], K/V from y[(b&31)*32 + (b>>5)]  (verified R2/R3).
// R4: spill-free phase-separated design.
//   S^T = K*Qs^T via mfma 16x16x32 (Qs prescaled by scale*log2e)
//   P stays in registers: S^T C-layout == 16x16x16 A-layout  -> PV via mfma 16x16x16
//   O_h overwrites Q_h in LDS (wave-local rows) -> out-proj via mfma 16x16x32
// LDS 69.6 KB -> 2 blocks/CU. ONE __syncthreads total.

#define NSET 32
#define SEQL 256
#define DM   20
#define NH   2
#define DH   20

typedef __attribute__((ext_vector_type(8))) short short8;
typedef __attribute__((ext_vector_type(4))) short short4v;
typedef __attribute__((ext_vector_type(4))) float f32x4;

#define MFMA32(a, b, c) __builtin_amdgcn_mfma_f32_16x16x32_bf16((a), (b), (c), 0, 0, 0)

#if __has_builtin(__builtin_amdgcn_mfma_f32_16x16x16bf16_1k)
#define MFMA16(a, b, c) __builtin_amdgcn_mfma_f32_16x16x16bf16_1k((a), (b), (c), 0, 0, 0)
#elif __has_builtin(__builtin_amdgcn_mfma_f32_16x16x16_bf16)
#define MFMA16(a, b, c) __builtin_amdgcn_mfma_f32_16x16x16_bf16((a), (b), (c), 0, 0, 0)
#else
static __device__ __forceinline__ f32x4 MFMA16(short4v a, short4v b, f32x4 c) {
    asm volatile("s_nop 1\n\tv_mfma_f32_16x16x16_bf16 %0, %1, %2, %0\n\ts_nop 7"
                 : "+v"(c) : "v"(a), "v"(b));
    return c;
}
#endif

__device__ __forceinline__ uint32_t bfbits_rne(float f) {
    uint32_t u = __float_as_uint(f);
    return ((u + 0x7fffu + ((u >> 16) & 1u)) >> 16) & 0xffffu;
}
__device__ __forceinline__ float fexp2(float x) {
    float r;
    asm("v_exp_f32 %0, %1" : "=v"(r) : "v"(x));
    return r;
}

// predicated b128 A/B-frag load from row-major [256][24] bf16 region
__device__ __forceinline__ short8 ldsA(const short* base, int row, int qd) {
    short8 f = {0, 0, 0, 0, 0, 0, 0, 0};
    if (qd < 3) f = *(const short8*)(base + row * 24 + qd * 8);
    return f;
}

// global fp32 row (20 floats, 16B-aligned) -> bf16 frag for k-quad qd
__device__ __forceinline__ short8 gfrag(const float* rowp, int qd) {
    short8 f = {0, 0, 0, 0, 0, 0, 0, 0};
    if (qd < 2) {
        float4 a = *(const float4*)(rowp + qd * 8);
        float4 b = *(const float4*)(rowp + qd * 8 + 4);
        f[0] = (short)bfbits_rne(a.x); f[1] = (short)bfbits_rne(a.y);
        f[2] = (short)bfbits_rne(a.z); f[3] = (short)bfbits_rne(a.w);
        f[4] = (short)bfbits_rne(b.x); f[5] = (short)bfbits_rne(b.y);
        f[6] = (short)bfbits_rne(b.z); f[7] = (short)bfbits_rne(b.w);
    } else if (qd == 2) {
        float4 a = *(const float4*)(rowp + 16);
        f[0] = (short)bfbits_rne(a.x); f[1] = (short)bfbits_rne(a.y);
        f[2] = (short)bfbits_rne(a.z); f[3] = (short)bfbits_rne(a.w);
    }
    return f;
}

__global__ __launch_bounds__(256, 2) void set_attn_v4(
    const float* __restrict__ x, const float* __restrict__ y,
    const float* __restrict__ wq, const float* __restrict__ wk,
    const float* __restrict__ wv, const float* __restrict__ wh,
    float* __restrict__ out)
{
    __shared__ __align__(16) short sQ[2 * SEQL * 24];   // [h][row][24], Q then O, 24 KB
    __shared__ __align__(16) short sK[2 * SEQL * 24];   // 24 KB
    __shared__ __align__(16) short sVt[40 * 264];       // V^T [h*20+d][s], 21.1 KB
    __shared__ float sL[256];                           // per-row softmax denom, 1 KB

    const int tid  = threadIdx.x;
    const int lane = tid & 63;
    const int w    = tid >> 6;
    const int c    = lane & 15;
    const int qd   = lane >> 4;
    const int b    = blockIdx.x;
    const int bi   = b >> 5, bj = b & 31;

    // zero pad cols 20..23 (read by qd==2 frags)
#pragma unroll
    for (int h = 0; h < 2; ++h) {
        *(uint2*)(sQ + h * 6144 + tid * 24 + 20) = make_uint2(0u, 0u);
        *(uint2*)(sK + h * 6144 + tid * 24 + 20) = make_uint2(0u, 0u);
    }

    const float QS = 0.22360679774997896f * 1.4426950408889634f;  // scale * log2(e)

    // ---- projection weight B-frags (global gather; live in this phase only) ----
    short8 wqf[2][2], wkf[2][2], wvf[2][2];
#pragma unroll
    for (int h = 0; h < 2; ++h)
#pragma unroll
        for (int dt = 0; dt < 2; ++dt) {
            int n = dt * 16 + c;
            short8 fq = {0,0,0,0,0,0,0,0}, fk = fq, fv = fq;
            if (n < 20) {
#pragma unroll
                for (int j = 0; j < 8; ++j) {
                    int k = qd * 8 + j;
                    if (k < 20) {
                        fq[j] = (short)bfbits_rne(wq[k * 40 + h * 20 + n]);
                        fk[j] = (short)bfbits_rne(wk[k * 40 + h * 20 + n]);
                        fv[j] = (short)bfbits_rne(wv[k * 40 + h * 20 + n]);
                    }
                }
            }
            wqf[h][dt] = fq; wkf[h][dt] = fk; wvf[h][dt] = fv;
        }

    // ---- projection: Q (prescaled), K, V^T for BOTH heads, x/y read once ----
#pragma unroll
    for (int mt = 0; mt < 4; ++mt) {
        int rbase = w * 64 + mt * 16;
        short8 xf = gfrag(x + ((size_t)b * SEQL + rbase + c) * DM, qd);
        short8 yf = gfrag(y + ((size_t)(bj * NSET + bi) * SEQL + rbase + c) * DM, qd);
#pragma unroll
        for (int h = 0; h < 2; ++h)
#pragma unroll
            for (int dt = 0; dt < 2; ++dt) {
                f32x4 z = {0.f, 0.f, 0.f, 0.f};
                f32x4 qres = MFMA32(xf, wqf[h][dt], z);
                f32x4 kres = MFMA32(yf, wkf[h][dt], z);
                f32x4 vres = MFMA32(yf, wvf[h][dt], z);
                int n = dt * 16 + c;
                if (n < 20) {
#pragma unroll
                    for (int reg = 0; reg < 4; ++reg) {
                        int row = rbase + qd * 4 + reg;
                        sQ[h * 6144 + row * 24 + n] = (short)bfbits_rne(qres[reg] * QS);
                        sK[h * 6144 + row * 24 + n] = (short)bfbits_rne(kres[reg]);
                        sVt[(h * 20 + n) * 264 + row] = (short)bfbits_rne(vres[reg]);
                    }
                }
            }
    }
    __syncthreads();   // the ONLY barrier: sK/sVt become read-only cross-wave

    f32x4 outacc[4][2];
#pragma unroll
    for (int mt = 0; mt < 4; ++mt)
#pragma unroll
        for (int dt = 0; dt < 2; ++dt) outacc[mt][dt] = (f32x4){0.f, 0.f, 0.f, 0.f};

    for (int h = 0; h < NH; ++h) {
        const short* Qh = sQ + h * 6144;
        const short* Kh = sK + h * 6144;

        short8 qb[4];
#pragma unroll
        for (int mt = 0; mt < 4; ++mt) qb[mt] = ldsA(Qh, w * 64 + mt * 16 + c, qd);

        f32x4 oacc[4][2];
#pragma unroll
        for (int mt = 0; mt < 4; ++mt)
#pragma unroll
            for (int dt = 0; dt < 2; ++dt) oacc[mt][dt] = (f32x4){0.f, 0.f, 0.f, 0.f};
        float ls0 = 0.f, ls1 = 0.f, ls2 = 0.f, ls3 = 0.f;

        for (int s0 = 0; s0 < SEQL; s0 += 32) {
            short8 kf0 = ldsA(Kh, s0 + c, qd);
            short8 kf1 = ldsA(Kh, s0 + 16 + c, qd);
            short4v vb[2][2];
#pragma unroll
            for (int dt = 0; dt < 2; ++dt) {
                int d = dt * 16 + c;
#pragma unroll
                for (int st = 0; st < 2; ++st) {
                    uint2 u = make_uint2(0u, 0u);
                    if (d < 20)
                        u = *(const uint2*)(sVt + (h * 20 + d) * 264 + s0 + st * 16 + qd * 4);
                    short4v t; *(uint2*)&t = u;
                    vb[st][dt] = t;
                }
            }
#pragma unroll
            for (int mt = 0; mt < 4; ++mt) {
#pragma unroll
                for (int st = 0; st < 2; ++st) {
                    f32x4 z = {0.f, 0.f, 0.f, 0.f};
                    f32x4 sacc = MFMA32((st == 0 ? kf0 : kf1), qb[mt], z);
                    float p0, p1, p2, p3;
                    {
                        float v0 = sacc[0], v1 = sacc[1], v2 = sacc[2], v3 = sacc[3];
                        p0 = (v0 != 0.f) ? fexp2(v0) : 0.f;   // zero-logit mask
                        p1 = (v1 != 0.f) ? fexp2(v1) : 0.f;
                        p2 = (v2 != 0.f) ? fexp2(v2) : 0.f;
                        p3 = (v3 != 0.f) ? fexp2(v3) : 0.f;
                    }
                    float lsum = (p0 + p1) + (p2 + p3);
                    if (mt == 0) ls0 += lsum;
                    else if (mt == 1) ls1 += lsum;
                    else if (mt == 2) ls2 += lsum;
                    else ls3 += lsum;
                    short4v pf;
                    *(uint2*)&pf = make_uint2(bfbits_rne(p0) | (bfbits_rne(p1) << 16),
                                              bfbits_rne(p2) | (bfbits_rne(p3) << 16));
                    oacc[mt][0] = MFMA16(pf, vb[st][0], oacc[mt][0]);
                    oacc[mt][1] = MFMA16(pf, vb[st][1], oacc[mt][1]);
                }
            }
        }

        // ---- softmax denominators: reduce over qd groups, broadcast via sL ----
        ls0 += __shfl_xor(ls0, 16, 64); ls0 += __shfl_xor(ls0, 32, 64);
        ls1 += __shfl_xor(ls1, 16, 64); ls1 += __shfl_xor(ls1, 32, 64);
        ls2 += __shfl_xor(ls2, 16, 64); ls2 += __shfl_xor(ls2, 32, 64);
        ls3 += __shfl_xor(ls3, 16, 64); ls3 += __shfl_xor(ls3, 32, 64);
        float sel = ls0;
        if (qd == 1) sel = ls1;
        if (qd == 2) sel = ls2;
        if (qd == 3) sel = ls3;
        sL[w * 64 + lane] = sel;   // sL[w*64 + i] = denom of row i (same-wave ordered)

        // ---- normalize O, overwrite Q_h slice (wave-local rows) ----
#pragma unroll
        for (int mt = 0; mt < 4; ++mt) {
            float inv[4];
#pragma unroll
            for (int reg = 0; reg < 4; ++reg)
                inv[reg] = 1.f / (sL[w * 64 + mt * 16 + qd * 4 + reg] + 1e-10f);
#pragma unroll
            for (int dt = 0; dt < 2; ++dt) {
                int n = dt * 16 + c;
                if (n < 20) {
#pragma unroll
                    for (int reg = 0; reg < 4; ++reg) {
                        int row = w * 64 + mt * 16 + qd * 4 + reg;
                        sQ[h * 6144 + row * 24 + n] =
                            (short)bfbits_rne(oacc[mt][dt][reg] * inv[reg]);
                    }
                }
            }
        }

        // ---- out-projection: outacc += O_h * WH[h*20:(h+1)*20, :] ----
        short8 whf[2];
#pragma unroll
        for (int dt = 0; dt < 2; ++dt) {
            int n = dt * 16 + c;
            short8 f = {0,0,0,0,0,0,0,0};
            if (n < 20) {
#pragma unroll
                for (int j = 0; j < 8; ++j) {
                    int k = qd * 8 + j;
                    if (k < 20) f[j] = (short)bfbits_rne(wh[(h * 20 + k) * 20 + n]);
                }
            }
            whf[dt] = f;
        }
#pragma unroll
        for (int mt = 0; mt < 4; ++mt) {
            short8 of = ldsA(Qh, w * 64 + mt * 16 + c, qd);   // same-wave rows
            outacc[mt][0] = MFMA32(of, whf[0], outacc[mt][0]);
            outacc[mt][1] = MFMA32(of, whf[1], outacc[mt][1]);
        }
    }

    // ---- store fp32 output ----
    float* ob = out + (size_t)b * (SEQL * DH);
#pragma unroll
    for (int mt = 0; mt < 4; ++mt)
#pragma unroll
        for (int dt = 0; dt < 2; ++dt) {
            int n = dt * 16 + c;
            if (n < 20) {
#pragma unroll
                for (int reg = 0; reg < 4; ++reg) {
                    int row = w * 64 + mt * 16 + qd * 4 + reg;
                    ob[row * 20 + n] = outacc[mt][dt][reg];
                }
            }
        }
}

extern "C" void kernel_launch(void* const* d_in, const int* in_sizes, int n_in,
                              void* d_out, int out_size, void* d_ws, size_t ws_size,
                              hipStream_t stream) {
    const float* x  = (const float*)d_in[0];
    const float* y  = (const float*)d_in[1];
    const float* wq = (const float*)d_in[2];
    const float* wk = (const float*)d_in[3];
    const float* wv = (const float*)d_in[4];
    const float* wh = (const float*)d_in[5];
    float* out = (float*)d_out;

    set_attn_v4<<<dim3(NSET * NSET), dim3(SEQL), 0, stream>>>(x, y, wq, wk, wv, wh, out);
}